// Round 2
// baseline (1005.715 us; speedup 1.0000x reference)
//
#include <hip/hip_runtime.h>
#include <math.h>

#define NB  32
#define NLQ 2048
#define NLK 2048
#define ND  128
#define KT  64
#define SCALE 11.3137084989847603904f  /* sqrt(128) — bug kept: MULTIPLY by sqrt(dk) */

typedef float f32x4 __attribute__((ext_vector_type(4)));
typedef short s16x8 __attribute__((ext_vector_type(8)));
typedef unsigned short u16;
typedef unsigned short u16x8 __attribute__((ext_vector_type(8)));

__device__ int g_maskflag;

static __device__ __forceinline__ u16 f2bf(float x) {
    unsigned int u = __float_as_uint(x);
    return (u16)((u + 0x7FFFu + ((u >> 16) & 1u)) >> 16);
}
static __device__ __forceinline__ float bf2f(u16 b) {
    return __uint_as_float(((unsigned int)b) << 16);
}

#define SPLIT8(H, L, J, VAL) do { float _v = (VAL); u16 _hb = f2bf(_v); \
    (H)[J] = (short)_hb; (L)[J] = (short)f2bf(_v - bf2f(_hb)); } while (0)

// global_load_lds: LDS dst is wave-uniform base (+ lane*16 by HW); global src is per-lane.
#define GLDS(lds, src) __builtin_amdgcn_global_load_lds( \
    (const __attribute__((address_space(1))) unsigned int*)(src), \
    (__attribute__((address_space(3))) unsigned int*)(lds), 16, 0, 0)

__global__ void zero_flag_kernel() { if (threadIdx.x == 0) g_maskflag = 0; }

// Mask dtype probe: bytes at offset 1 (mod 4) are 0 for int32 layout, ~10% nonzero
// for byte layout. Ballot per wave -> at most 1 atomic per wave (no atomic storm).
__global__ void detect_mask_kernel(const unsigned char* __restrict__ m) {
    unsigned int i = blockIdx.x * blockDim.x + threadIdx.x;
    bool nz = m[(size_t)i * 4 + 1] != 0;
    if (__any((int)nz) && (threadIdx.x & 63) == 0) atomicOr(&g_maskflag, 1);
}

// ---- precompute: K -> split bf16 hi/lo, pre-swizzled 64x128 tiles ----
// tile layout: ushort index (kk*128 + d) ^ ((kk&7)<<3); linear LDS fill == swizzled tile.
__global__ void __launch_bounds__(256)
ksplit_kernel(const float* __restrict__ K, u16* __restrict__ Khi, u16* __restrict__ Klo) {
    int idx  = blockIdx.x * 256 + threadIdx.x;   // one 8-elem chunk per thread
    int d0   = (idx & 15) << 3;
    int krow = idx >> 4;                         // global k row (b*2048 + kk)
    const float* src = K + (size_t)krow * ND + d0;
    float4 x0 = *(const float4*)src;
    float4 x1 = *(const float4*)(src + 4);
    float xs[8] = {x0.x, x0.y, x0.z, x0.w, x1.x, x1.y, x1.z, x1.w};
    u16x8 h, l;
    #pragma unroll
    for (int j = 0; j < 8; ++j) { u16 hb = f2bf(xs[j]); h[j] = hb; l[j] = f2bf(xs[j] - bf2f(hb)); }
    int kkl = krow & 63;
    size_t tbase = ((size_t)(krow >> 6)) * 8192;     // (b*32 + ktile) * 8192
    int off = (kkl * ND + d0) ^ ((kkl & 7) << 3);
    *(u16x8*)(Khi + tbase + off) = h;
    *(u16x8*)(Klo + tbase + off) = l;
}

// ---- precompute: V -> bf16 transposed [d=128][k=64] tiles, pre-swizzled ----
// tile layout: ushort index (d*64 + kk) ^ ((d&7)<<3)
__global__ void __launch_bounds__(256)
vtrans_kernel(const float* __restrict__ V, u16* __restrict__ Vt) {
    int gw = (blockIdx.x * 256 + threadIdx.x) >> 6;  // wave id: 16 waves per tile
    int ln = threadIdx.x & 63;
    int dgrp = gw & 15;
    int tile = gw >> 4;                              // b*32 + ktile
    int dl = ln >> 3, chunk = ln & 7;
    int d = dgrp * 8 + dl;
    int kk0 = chunk * 8;
    const float* src = V + ((size_t)tile * 64 + kk0) * ND + d;
    u16x8 o;
    #pragma unroll
    for (int j = 0; j < 8; ++j) o[j] = f2bf(src[(size_t)j * ND]);
    *(u16x8*)(Vt + (size_t)tile * 8192 + ((d * KT + kk0) ^ ((d & 7) << 3))) = o;
}

// ==================== main attention: 512 blocks, 128 q-rows/block ====================
__global__ void __launch_bounds__(256, 2)
attn2_kernel(const float* __restrict__ Q, const unsigned char* __restrict__ Mb,
             float* __restrict__ Out,
             const u16* __restrict__ Khi, const u16* __restrict__ Klo,
             const u16* __restrict__ Vt)
{
    __shared__ u16 sKh[KT * ND];        // 16KB, swizzled (filled linearly by GLDS)
    __shared__ u16 sKl[KT * ND];        // 16KB
    __shared__ u16 sVt[ND * KT];        // 16KB
    __shared__ u16 sP[4][2][16 * KT];   // 16KB: per-wave, per-q-group P

    const int tid  = threadIdx.x;
    const int wave = tid >> 6;
    const int ln   = tid & 63;
    const int g    = ln >> 4;
    const int qi   = ln & 15;

    // XCD swizzle: XCD x gets contiguous orig range -> 4 batches per XCD (L2 locality)
    const int n    = blockIdx.x;
    const int orig = ((n & 7) << 6) | (n >> 3);
    const int b    = orig >> 4;          // 16 blocks per batch
    const int qt   = orig & 15;
    const int qbase = qt * 128 + wave * 32;   // this wave's 32 q rows

    const bool maskByte = (g_maskflag != 0);

    // ---- Q fragments: 2 q-groups, scaled, split hi/lo ----
    s16x8 qh8[2][4], ql8[2][4];
    #pragma unroll
    for (int u = 0; u < 2; ++u) {
        const float* qp = Q + ((size_t)b * NLQ + qbase + u * 16 + qi) * ND;
        #pragma unroll
        for (int c = 0; c < 4; ++c) {
            const float* p = qp + c * 32 + g * 8;
            float4 x0 = *(const float4*)(p);
            float4 x1 = *(const float4*)(p + 4);
            s16x8 h, l;
            SPLIT8(h, l, 0, x0.x * SCALE); SPLIT8(h, l, 1, x0.y * SCALE);
            SPLIT8(h, l, 2, x0.z * SCALE); SPLIT8(h, l, 3, x0.w * SCALE);
            SPLIT8(h, l, 4, x1.x * SCALE); SPLIT8(h, l, 5, x1.y * SCALE);
            SPLIT8(h, l, 6, x1.z * SCALE); SPLIT8(h, l, 7, x1.w * SCALE);
            qh8[u][c] = h; ql8[u][c] = l;
        }
    }

    f32x4 o[2][8];
    #pragma unroll
    for (int u = 0; u < 2; ++u)
        #pragma unroll
        for (int t = 0; t < 8; ++t) o[u][t] = (f32x4){0.f, 0.f, 0.f, 0.f};
    float mrun[2] = {-INFINITY, -INFINITY}, lsum[2] = {0.f, 0.f};

    const size_t mrow0 = ((size_t)b * NLQ + qbase + qi) * (size_t)NLK;
    const size_t mrow1 = mrow0 + (size_t)16 * NLK;

    const u16* khT = Khi + (size_t)b * 32 * 8192;
    const u16* klT = Klo + (size_t)b * 32 * 8192;
    const u16* vtT = Vt  + (size_t)b * 32 * 8192;

    for (int kt = 0; kt < NLK / KT; ++kt) {
        const int kb = kt * KT;
        __syncthreads();   // all waves done reading previous tile

        // ---- stage K(hi,lo) + Vt via global_load_lds (pre-swizzled source) ----
        {
            const char* s0 = (const char*)(khT + (size_t)kt * 8192) + (size_t)wave * 1024 + (size_t)ln * 16;
            const char* s1 = (const char*)(klT + (size_t)kt * 8192) + (size_t)wave * 1024 + (size_t)ln * 16;
            const char* s2 = (const char*)(vtT + (size_t)kt * 8192) + (size_t)wave * 1024 + (size_t)ln * 16;
            #pragma unroll
            for (int i = 0; i < 4; ++i) {
                GLDS(&sKh[i * 2048 + wave * 512], s0 + i * 4096);
                GLDS(&sKl[i * 2048 + wave * 512], s1 + i * 4096);
                GLDS(&sVt[i * 2048 + wave * 512], s2 + i * 4096);
            }
        }

        // ---- mask bits for both q-groups (overlaps staging latency) ----
        unsigned mbitsA[2];
        if (maskByte) {
            #pragma unroll
            for (int u = 0; u < 2; ++u) {
                size_t mrow = u ? mrow1 : mrow0;
                unsigned bits = 0;
                #pragma unroll
                for (int s = 0; s < 4; ++s) {
                    unsigned mm = *(const unsigned*)(Mb + mrow + (size_t)(kb + s * 16 + 4 * g));
                    #pragma unroll
                    for (int j = 0; j < 4; ++j)
                        bits |= (((mm >> (8 * j)) & 0xFFu) ? 1u : 0u) << (s * 4 + j);
                }
                mbitsA[u] = bits;
            }
        } else {
            const int* Mi = (const int*)Mb;
            #pragma unroll
            for (int u = 0; u < 2; ++u) {
                size_t mrow = u ? mrow1 : mrow0;
                unsigned bits = 0;
                #pragma unroll
                for (int s = 0; s < 4; ++s) {
                    int4 mm = *(const int4*)(Mi + mrow + (size_t)(kb + s * 16 + 4 * g));
                    if (mm.x) bits |= 1u << (s * 4 + 0);
                    if (mm.y) bits |= 1u << (s * 4 + 1);
                    if (mm.z) bits |= 1u << (s * 4 + 2);
                    if (mm.w) bits |= 1u << (s * 4 + 3);
                }
                mbitsA[u] = bits;
            }
        }
        __syncthreads();   // staging complete (barrier drains vmcnt)

        // ---- QK^T: 3-pass split MFMA, both q-groups share the K fragment reads ----
        float p[2][16];
        #pragma unroll
        for (int s = 0; s < 4; ++s) {
            f32x4 a0 = (f32x4){0.f, 0.f, 0.f, 0.f};
            f32x4 a1 = (f32x4){0.f, 0.f, 0.f, 0.f};
            int row = s * 16 + qi;
            int rowoff = row * ND, swz = (row & 7) << 3;
            #pragma unroll
            for (int c = 0; c < 4; ++c) {
                int off = (rowoff + c * 32 + g * 8) ^ swz;
                s16x8 kh = *(s16x8*)&sKh[off];
                s16x8 kl = *(s16x8*)&sKl[off];
                a0 = __builtin_amdgcn_mfma_f32_16x16x32_bf16(kh, qh8[0][c], a0, 0, 0, 0);
                a1 = __builtin_amdgcn_mfma_f32_16x16x32_bf16(kh, qh8[1][c], a1, 0, 0, 0);
                a0 = __builtin_amdgcn_mfma_f32_16x16x32_bf16(kh, ql8[0][c], a0, 0, 0, 0);
                a1 = __builtin_amdgcn_mfma_f32_16x16x32_bf16(kh, ql8[1][c], a1, 0, 0, 0);
                a0 = __builtin_amdgcn_mfma_f32_16x16x32_bf16(kl, qh8[0][c], a0, 0, 0, 0);
                a1 = __builtin_amdgcn_mfma_f32_16x16x32_bf16(kl, qh8[1][c], a1, 0, 0, 0);
            }
            #pragma unroll
            for (int r = 0; r < 4; ++r) { p[0][s * 4 + r] = a0[r]; p[1][s * 4 + r] = a1[r]; }
        }

        // ---- online softmax per q-group + P -> LDS ----
        #pragma unroll
        for (int u = 0; u < 2; ++u) {
            unsigned mbits = mbitsA[u];
            float tmax = -INFINITY;
            #pragma unroll
            for (int i = 0; i < 16; ++i) {
                float sv = ((mbits >> i) & 1u) ? -INFINITY : p[u][i];
                p[u][i] = sv;
                tmax = fmaxf(tmax, sv);
            }
            tmax = fmaxf(tmax, __shfl_xor(tmax, 16));
            tmax = fmaxf(tmax, __shfl_xor(tmax, 32));
            float mnew = fmaxf(mrun[u], tmax);
            float corr = (mnew == -INFINITY) ? 0.f : __expf(mrun[u] - mnew);
            float psum = 0.f;
            #pragma unroll
            for (int i = 0; i < 16; ++i) {
                float pv = ((mbits >> i) & 1u) ? 0.f : __expf(p[u][i] - mnew);
                p[u][i] = pv;
                psum += pv;
            }
            psum += __shfl_xor(psum, 16);
            psum += __shfl_xor(psum, 32);
            lsum[u] = lsum[u] * corr + psum;
            mrun[u] = mnew;
            #pragma unroll
            for (int j = 0; j < 4; ++j) {
                float cj = __shfl(corr, 4 * g + j, 64);
                #pragma unroll
                for (int t = 0; t < 8; ++t) o[u][t][j] *= cj;
            }
            #pragma unroll
            for (int s = 0; s < 4; ++s) {
                ushort4 p4;
                p4.x = f2bf(p[u][s * 4 + 0]); p4.y = f2bf(p[u][s * 4 + 1]);
                p4.z = f2bf(p[u][s * 4 + 2]); p4.w = f2bf(p[u][s * 4 + 3]);
                int off = (qi * KT + s * 16 + 4 * g) ^ ((qi & 7) << 3);
                *(ushort4*)&sP[wave][u][off] = p4;
            }
        }

        // ---- PV: V fragment reads shared by both q-groups ----
        #pragma unroll
        for (int h = 0; h < 2; ++h) {
            int offp = (qi * KT + h * 32 + g * 8) ^ ((qi & 7) << 3);
            s16x8 pa0 = *(s16x8*)&sP[wave][0][offp];
            s16x8 pa1 = *(s16x8*)&sP[wave][1][offp];
            #pragma unroll
            for (int t = 0; t < 8; ++t) {
                int d = t * 16 + qi;
                int offv = (d * KT + h * 32 + g * 8) ^ ((d & 7) << 3);
                s16x8 vb = *(s16x8*)&sVt[offv];
                o[0][t] = __builtin_amdgcn_mfma_f32_16x16x32_bf16(pa0, vb, o[0][t], 0, 0, 0);
                o[1][t] = __builtin_amdgcn_mfma_f32_16x16x32_bf16(pa1, vb, o[1][t], 0, 0, 0);
            }
        }
    }

    // ---- epilogue ----
    #pragma unroll
    for (int u = 0; u < 2; ++u)
        #pragma unroll
        for (int j = 0; j < 4; ++j) {
            float lj = __shfl(lsum[u], 4 * g + j, 64);
            float inv = (lj > 0.f) ? (1.0f / lj) : 0.f;
            int row = qbase + u * 16 + 4 * g + j;
            float* op = Out + ((size_t)b * NLQ + row) * ND + qi;
            #pragma unroll
            for (int t = 0; t < 8; ++t) op[t * 16] = o[u][t][j] * inv;
        }
}

// ==================== fallback (round-1 kernel) if ws too small ====================
__global__ void __launch_bounds__(256, 2)
attn_fallback(const float* __restrict__ Q, const float* __restrict__ K,
              const float* __restrict__ V, const unsigned char* __restrict__ Mb,
              float* __restrict__ Out)
{
    __shared__ u16 sKh[KT * ND];
    __shared__ u16 sKl[KT * ND];
    __shared__ u16 sVt[ND * KT];
    __shared__ u16 sP[4][16 * KT];

    const int tid  = threadIdx.x;
    const int wave = tid >> 6;
    const int ln   = tid & 63;
    const int g    = ln >> 4;
    const int qi   = ln & 15;

    const int bid   = blockIdx.x;
    const int b     = bid >> 5;
    const int qt    = bid & 31;
    const int qbase = qt * 64;
    const int qrow  = qbase + wave * 16 + qi;

    const bool maskByte = (g_maskflag != 0);

    s16x8 qh8[4], ql8[4];
    {
        const float* qp = Q + ((size_t)b * NLQ + qrow) * ND;
        #pragma unroll
        for (int c = 0; c < 4; ++c) {
            const float* p = qp + c * 32 + g * 8;
            float4 x0 = *(const float4*)(p);
            float4 x1 = *(const float4*)(p + 4);
            s16x8 h, l;
            SPLIT8(h, l, 0, x0.x * SCALE); SPLIT8(h, l, 1, x0.y * SCALE);
            SPLIT8(h, l, 2, x0.z * SCALE); SPLIT8(h, l, 3, x0.w * SCALE);
            SPLIT8(h, l, 4, x1.x * SCALE); SPLIT8(h, l, 5, x1.y * SCALE);
            SPLIT8(h, l, 6, x1.z * SCALE); SPLIT8(h, l, 7, x1.w * SCALE);
            qh8[c] = h; ql8[c] = l;
        }
    }

    f32x4 o[8];
    #pragma unroll
    for (int t = 0; t < 8; ++t) o[t] = (f32x4){0.f, 0.f, 0.f, 0.f};
    float m_run = -INFINITY, lsumv = 0.f;

    const float* kbp = K + (size_t)b * NLK * ND;
    const float* vbp = V + (size_t)b * NLK * ND;
    const size_t mrow = ((size_t)b * NLQ + qrow) * (size_t)NLK;

    for (int kt = 0; kt < NLK / KT; ++kt) {
        const int kb = kt * KT;
        __syncthreads();

        #pragma unroll
        for (int r = 0; r < 8; ++r) {
            int idx = r * 256 + tid;
            int kk  = idx >> 5;
            int d0  = (idx & 31) << 2;
            float4 x = *(const float4*)(kbp + (size_t)(kb + kk) * ND + d0);
            ushort4 h4, l4; u16 hb;
            hb = f2bf(x.x); h4.x = hb; l4.x = f2bf(x.x - bf2f(hb));
            hb = f2bf(x.y); h4.y = hb; l4.y = f2bf(x.y - bf2f(hb));
            hb = f2bf(x.z); h4.z = hb; l4.z = f2bf(x.z - bf2f(hb));
            hb = f2bf(x.w); h4.w = hb; l4.w = f2bf(x.w - bf2f(hb));
            int off = (kk * ND + d0) ^ ((kk & 7) << 3);
            *(ushort4*)&sKh[off] = h4;
            *(ushort4*)&sKl[off] = l4;
        }
        #pragma unroll
        for (int r = 0; r < 2; ++r) {
            int idx = r * 256 + tid;
            int kk0 = (idx >> 5) << 2;
            int d0  = (idx & 31) << 2;
            const float* vp = vbp + (size_t)(kb + kk0) * ND + d0;
            float4 r0 = *(const float4*)(vp);
            float4 r1 = *(const float4*)(vp + ND);
            float4 r2 = *(const float4*)(vp + 2 * ND);
            float4 r3 = *(const float4*)(vp + 3 * ND);
            ushort4 cv;
            cv.x = f2bf(r0.x); cv.y = f2bf(r1.x); cv.z = f2bf(r2.x); cv.w = f2bf(r3.x);
            { int d = d0;     *(ushort4*)&sVt[(d * KT + kk0) ^ ((d & 7) << 3)] = cv; }
            cv.x = f2bf(r0.y); cv.y = f2bf(r1.y); cv.z = f2bf(r2.y); cv.w = f2bf(r3.y);
            { int d = d0 + 1; *(ushort4*)&sVt[(d * KT + kk0) ^ ((d & 7) << 3)] = cv; }
            cv.x = f2bf(r0.z); cv.y = f2bf(r1.z); cv.z = f2bf(r2.z); cv.w = f2bf(r3.z);
            { int d = d0 + 2; *(ushort4*)&sVt[(d * KT + kk0) ^ ((d & 7) << 3)] = cv; }
            cv.x = f2bf(r0.w); cv.y = f2bf(r1.w); cv.z = f2bf(r2.w); cv.w = f2bf(r3.w);
            { int d = d0 + 3; *(ushort4*)&sVt[(d * KT + kk0) ^ ((d & 7) << 3)] = cv; }
        }
        __syncthreads();

        unsigned maskbits = 0;
        if (maskByte) {
            #pragma unroll
            for (int s = 0; s < 4; ++s) {
                unsigned mm = *(const unsigned int*)(Mb + mrow + (size_t)(kb + s * 16 + 4 * g));
                #pragma unroll
                for (int j = 0; j < 4; ++j)
                    maskbits |= (((mm >> (8 * j)) & 0xFFu) ? 1u : 0u) << (s * 4 + j);
            }
        } else {
            const int* Mi = (const int*)Mb;
            #pragma unroll
            for (int s = 0; s < 4; ++s) {
                int4 mm = *(const int4*)(Mi + mrow + (size_t)(kb + s * 16 + 4 * g));
                if (mm.x) maskbits |= 1u << (s * 4 + 0);
                if (mm.y) maskbits |= 1u << (s * 4 + 1);
                if (mm.z) maskbits |= 1u << (s * 4 + 2);
                if (mm.w) maskbits |= 1u << (s * 4 + 3);
            }
        }

        float p[16];
        #pragma unroll
        for (int s = 0; s < 4; ++s) {
            f32x4 acc = (f32x4){0.f, 0.f, 0.f, 0.f};
            int rowoff = (s * 16 + qi) * ND;
            int swz = ((s * 16 + qi) & 7) << 3;
            #pragma unroll
            for (int c = 0; c < 4; ++c) {
                int off = (rowoff + c * 32 + g * 8) ^ swz;
                s16x8 kh = *(s16x8*)&sKh[off];
                s16x8 kl = *(s16x8*)&sKl[off];
                acc = __builtin_amdgcn_mfma_f32_16x16x32_bf16(kh, qh8[c], acc, 0, 0, 0);
                acc = __builtin_amdgcn_mfma_f32_16x16x32_bf16(kh, ql8[c], acc, 0, 0, 0);
                acc = __builtin_amdgcn_mfma_f32_16x16x32_bf16(kl, qh8[c], acc, 0, 0, 0);
            }
            p[s * 4 + 0] = acc[0]; p[s * 4 + 1] = acc[1];
            p[s * 4 + 2] = acc[2]; p[s * 4 + 3] = acc[3];
        }

        float tmax = -INFINITY;
        #pragma unroll
        for (int i = 0; i < 16; ++i) {
            float sv = ((maskbits >> i) & 1u) ? -INFINITY : p[i];
            p[i] = sv;
            tmax = fmaxf(tmax, sv);
        }
        tmax = fmaxf(tmax, __shfl_xor(tmax, 16));
        tmax = fmaxf(tmax, __shfl_xor(tmax, 32));
        float mnew = fmaxf(m_run, tmax);
        float corr = (mnew == -INFINITY) ? 0.f : __expf(m_run - mnew);
        float psum = 0.f;
        #pragma unroll
        for (int i = 0; i < 16; ++i) {
            float pv = ((maskbits >> i) & 1u) ? 0.f : __expf(p[i] - mnew);
            p[i] = pv;
            psum += pv;
        }
        psum += __shfl_xor(psum, 16);
        psum += __shfl_xor(psum, 32);
        lsumv = lsumv * corr + psum;
        m_run = mnew;

        #pragma unroll
        for (int j = 0; j < 4; ++j) {
            float cj = __shfl(corr, 4 * g + j, 64);
            #pragma unroll
            for (int t = 0; t < 8; ++t) o[t][j] *= cj;
        }

        #pragma unroll
        for (int s = 0; s < 4; ++s) {
            ushort4 p4;
            p4.x = f2bf(p[s * 4 + 0]); p4.y = f2bf(p[s * 4 + 1]);
            p4.z = f2bf(p[s * 4 + 2]); p4.w = f2bf(p[s * 4 + 3]);
            int off = (qi * KT + s * 16 + 4 * g) ^ ((qi & 7) << 3);
            *(ushort4*)&sP[wave][off] = p4;
        }
        #pragma unroll
        for (int h = 0; h < 2; ++h) {
            int offp = (qi * KT + h * 32 + g * 8) ^ ((qi & 7) << 3);
            s16x8 pa = *(s16x8*)&sP[wave][offp];
            #pragma unroll
            for (int t = 0; t < 8; ++t) {
                int d = t * 16 + qi;
                int offv = (d * KT + h * 32 + g * 8) ^ ((d & 7) << 3);
                s16x8 vb = *(s16x8*)&sVt[offv];
                o[t] = __builtin_amdgcn_mfma_f32_16x16x32_bf16(pa, vb, o[t], 0, 0, 0);
            }
        }
    }

    #pragma unroll
    for (int j = 0; j < 4; ++j) {
        float lj = __shfl(lsumv, 4 * g + j, 64);
        float inv = (lj > 0.f) ? (1.0f / lj) : 0.f;
        int row = qbase + wave * 16 + 4 * g + j;
        float* op = Out + ((size_t)b * NLQ + row) * ND + qi;
        #pragma unroll
        for (int t = 0; t < 8; ++t) op[t * 16] = o[t][j] * inv;
    }
}

extern "C" void kernel_launch(void* const* d_in, const int* in_sizes, int n_in,
                              void* d_out, int out_size, void* d_ws, size_t ws_size,
                              hipStream_t stream) {
    (void)in_sizes; (void)n_in; (void)out_size;
    const float* Q = (const float*)d_in[0];
    const float* K = (const float*)d_in[1];
    const float* V = (const float*)d_in[2];
    const unsigned char* M = (const unsigned char*)d_in[3];
    float* Out = (float*)d_out;

    zero_flag_kernel<<<1, 64, 0, stream>>>();
    detect_mask_kernel<<<64, 256, 0, stream>>>(M);

    const size_t WS_NEED = (size_t)48 * 1024 * 1024;  // Khi 16M + Klo 16M + Vt 16M
    if (ws_size >= WS_NEED) {
        u16* Khi = (u16*)d_ws;
        u16* Klo = Khi + 8388608;
        u16* Vt  = Klo + 8388608;
        ksplit_kernel<<<4096, 256, 0, stream>>>(K, Khi, Klo);
        vtrans_kernel<<<4096, 256, 0, stream>>>(V, Vt);
        attn2_kernel<<<512, 256, 0, stream>>>(Q, M, Out, Khi, Klo, Vt);
    } else {
        attn_fallback<<<1024, 256, 0, stream>>>(Q, K, V, M, Out);
    }
}

// Round 3
// 964.211 us; speedup vs baseline: 1.0430x; 1.0430x over previous
//
#include <hip/hip_runtime.h>
#include <math.h>

#define NB  32
#define NLQ 2048
#define NLK 2048
#define ND  128
#define KT  64
/* bug kept: MULTIPLY by sqrt(dk); fold log2(e) so softmax runs in exp2 domain */
#define SCALE2 16.3231239813435843f   /* sqrt(128) * log2(e) */
#define SCALE  11.3137084989847603904f

typedef float f32x4 __attribute__((ext_vector_type(4)));
typedef short s16x8 __attribute__((ext_vector_type(8)));
typedef unsigned short u16;
typedef unsigned short u16x8 __attribute__((ext_vector_type(8)));
typedef unsigned long long u64;

__device__ int g_maskflag;

static __device__ __forceinline__ u16 f2bf(float x) {
    unsigned int u = __float_as_uint(x);
    return (u16)((u + 0x7FFFu + ((u >> 16) & 1u)) >> 16);
}
static __device__ __forceinline__ float bf2f(u16 b) {
    return __uint_as_float(((unsigned int)b) << 16);
}

#define SPLIT8(H, L, J, VAL) do { float _v = (VAL); u16 _hb = f2bf(_v); \
    (H)[J] = (short)_hb; (L)[J] = (short)f2bf(_v - bf2f(_hb)); } while (0)

#define GLDS(lds, src) __builtin_amdgcn_global_load_lds( \
    (const __attribute__((address_space(1))) unsigned int*)(src), \
    (__attribute__((address_space(3))) unsigned int*)(lds), 16, 0, 0)

__global__ void zero_flag_kernel() { if (threadIdx.x == 0) g_maskflag = 0; }

// Mask dtype probe: bytes at offset 1 (mod 4) are 0 for int32 layout, ~10% nonzero
// for byte layout. 1 atomic per wave max.
__global__ void detect_mask_kernel(const unsigned char* __restrict__ m) {
    unsigned int i = blockIdx.x * blockDim.x + threadIdx.x;
    bool nz = m[(size_t)i * 4 + 1] != 0;
    if (__any((int)nz) && (threadIdx.x & 63) == 0) atomicOr(&g_maskflag, 1);
}

// ---- mask -> bit-matrix. word w covers entries [w*64, w*64+64); bit j = lane j's entry.
// Contiguous 256B (int32) / 64B (byte) per wave-iteration -> full-BW stream.
__global__ void __launch_bounds__(256)
maskbits_kernel(const unsigned char* __restrict__ M, u64* __restrict__ Bits) {
    const size_t NWORDS = (size_t)NB * NLQ * (NLK / 64);   // 2,097,152
    const int ln = threadIdx.x & 63;
    const size_t wgid = ((size_t)blockIdx.x * 256 + threadIdx.x) >> 6;
    const size_t NW = (size_t)4096 * 4;                    // total waves in grid
    if (g_maskflag != 0) {
        #pragma unroll 4
        for (size_t w = wgid; w < NWORDS; w += NW) {
            unsigned char v = M[w * 64 + ln];
            u64 bal = __ballot(v != 0);
            if (ln == 0) Bits[w] = bal;
        }
    } else {
        const int* Mi = (const int*)M;
        #pragma unroll 4
        for (size_t w = wgid; w < NWORDS; w += NW) {
            int v = Mi[w * 64 + ln];
            u64 bal = __ballot(v != 0);
            if (ln == 0) Bits[w] = bal;
        }
    }
}

// ---- precompute: K -> split bf16 hi/lo, pre-swizzled 64x128 tiles ----
__global__ void __launch_bounds__(256)
ksplit_kernel(const float* __restrict__ K, u16* __restrict__ Khi, u16* __restrict__ Klo) {
    int idx  = blockIdx.x * 256 + threadIdx.x;
    int d0   = (idx & 15) << 3;
    int krow = idx >> 4;
    const float* src = K + (size_t)krow * ND + d0;
    float4 x0 = *(const float4*)src;
    float4 x1 = *(const float4*)(src + 4);
    float xs[8] = {x0.x, x0.y, x0.z, x0.w, x1.x, x1.y, x1.z, x1.w};
    u16x8 h, l;
    #pragma unroll
    for (int j = 0; j < 8; ++j) { u16 hb = f2bf(xs[j]); h[j] = hb; l[j] = f2bf(xs[j] - bf2f(hb)); }
    int kkl = krow & 63;
    size_t tbase = ((size_t)(krow >> 6)) * 8192;
    int off = (kkl * ND + d0) ^ ((kkl & 7) << 3);
    *(u16x8*)(Khi + tbase + off) = h;
    *(u16x8*)(Klo + tbase + off) = l;
}

// ---- precompute: V -> bf16 transposed [d=128][k=64] tiles, pre-swizzled ----
__global__ void __launch_bounds__(256)
vtrans_kernel(const float* __restrict__ V, u16* __restrict__ Vt) {
    int gw = (blockIdx.x * 256 + threadIdx.x) >> 6;
    int ln = threadIdx.x & 63;
    int dgrp = gw & 15;
    int tile = gw >> 4;
    int dl = ln >> 3, chunk = ln & 7;
    int d = dgrp * 8 + dl;
    int kk0 = chunk * 8;
    const float* src = V + ((size_t)tile * 64 + kk0) * ND + d;
    u16x8 o;
    #pragma unroll
    for (int j = 0; j < 8; ++j) o[j] = f2bf(src[(size_t)j * ND]);
    *(u16x8*)(Vt + (size_t)tile * 8192 + ((d * KT + kk0) ^ ((d & 7) << 3))) = o;
}

// ==================== main attention ====================
// 256 blocks (1/CU), 512 threads (8 waves), 256 q-rows/block, 32 rows/wave (u=0,1).
// 128KB dynamic LDS: double-buffered {Kh,Kl,Vt} tiles + per-wave P.
__global__ void __launch_bounds__(512, 2)
attn3_kernel(const float* __restrict__ Q, const u64* __restrict__ Bits,
             float* __restrict__ Out,
             const u16* __restrict__ Khi, const u16* __restrict__ Klo,
             const u16* __restrict__ Vt)
{
    extern __shared__ u16 smem[];
    u16* bufA = smem;             // 24576 u16: Kh[8192] Kl[8192] Vt[8192]
    u16* bufB = smem + 24576;
    u16* sPb  = smem + 49152;     // 8 waves x 2 u x 1024 u16

    const int tid  = threadIdx.x;
    const int wave = tid >> 6;
    const int ln   = tid & 63;
    const int g    = ln >> 4;
    const int qi   = ln & 15;

    // XCD swizzle (bijective, 256 % 8 == 0): XCD x gets batches 4x..4x+3
    const int n    = blockIdx.x;
    const int orig = ((n & 7) << 5) | (n >> 3);
    const int b    = orig >> 3;
    const int qt   = orig & 7;
    const int qbase = qt * 256 + wave * 32;

    // ---- Q fragments: 2 q-groups, scaled (log2 domain), split hi/lo ----
    s16x8 qh8[2][4], ql8[2][4];
    #pragma unroll
    for (int u = 0; u < 2; ++u) {
        const float* qp = Q + ((size_t)b * NLQ + qbase + u * 16 + qi) * ND;
        #pragma unroll
        for (int c = 0; c < 4; ++c) {
            const float* p = qp + c * 32 + g * 8;
            float4 x0 = *(const float4*)(p);
            float4 x1 = *(const float4*)(p + 4);
            s16x8 h, l;
            SPLIT8(h, l, 0, x0.x * SCALE2); SPLIT8(h, l, 1, x0.y * SCALE2);
            SPLIT8(h, l, 2, x0.z * SCALE2); SPLIT8(h, l, 3, x0.w * SCALE2);
            SPLIT8(h, l, 4, x1.x * SCALE2); SPLIT8(h, l, 5, x1.y * SCALE2);
            SPLIT8(h, l, 6, x1.z * SCALE2); SPLIT8(h, l, 7, x1.w * SCALE2);
            qh8[u][c] = h; ql8[u][c] = l;
        }
    }

    f32x4 o[2][8];
    #pragma unroll
    for (int u = 0; u < 2; ++u)
        #pragma unroll
        for (int t = 0; t < 8; ++t) o[u][t] = (f32x4){0.f, 0.f, 0.f, 0.f};
    float mrun[2] = {-INFINITY, -INFINITY}, lsum[2] = {0.f, 0.f};

    const u16* khT = Khi + (size_t)b * 32 * 8192;
    const u16* klT = Klo + (size_t)b * 32 * 8192;
    const u16* vtT = Vt  + (size_t)b * 32 * 8192;

    const size_t row0 = (size_t)b * NLQ + qbase + qi;       // u=0 row for this lane
    const u64* bw0 = Bits + row0 * 32;
    const u64* bw1 = Bits + (row0 + 16) * 32;

#define STAGE_TILE(dst, kt_) do { \
    const char* _sK = (const char*)(khT + (size_t)(kt_) * 8192) + wave * 2048 + ln * 16; \
    const char* _sL = (const char*)(klT + (size_t)(kt_) * 8192) + wave * 2048 + ln * 16; \
    const char* _sV = (const char*)(vtT + (size_t)(kt_) * 8192) + wave * 2048 + ln * 16; \
    GLDS((dst) + wave * 1024,               _sK); \
    GLDS((dst) + wave * 1024 + 512,         _sK + 1024); \
    GLDS((dst) + 8192  + wave * 1024,       _sL); \
    GLDS((dst) + 8192  + wave * 1024 + 512, _sL + 1024); \
    GLDS((dst) + 16384 + wave * 1024,       _sV); \
    GLDS((dst) + 16384 + wave * 1024 + 512, _sV + 1024); \
} while (0)

    // prologue: stage tile 0, load mask words for tile 0
    STAGE_TILE(bufA, 0);
    u64 mw0 = bw0[0], mw1 = bw1[0];
    __syncthreads();

    u16* cur = bufA;
    u16* nxt = bufB;

    for (int kt = 0; kt < 32; ++kt) {
        u64 nmw0 = mw0, nmw1 = mw1;
        if (kt < 31) {                       // issue next-tile loads early (covered by compute)
            STAGE_TILE(nxt, kt + 1);
            nmw0 = bw0[kt + 1];
            nmw1 = bw1[kt + 1];
        }

        u16* sKh = cur;
        u16* sKl = cur + 8192;
        u16* sVt_ = cur + 16384;

        // ---- QK^T: 3-pass split MFMA, both q-groups share K fragment reads ----
        float p[2][16];
        #pragma unroll
        for (int s = 0; s < 4; ++s) {
            f32x4 a0 = (f32x4){0.f, 0.f, 0.f, 0.f};
            f32x4 a1 = (f32x4){0.f, 0.f, 0.f, 0.f};
            int row = s * 16 + qi;
            int rowoff = row * ND, swz = (row & 7) << 3;
            #pragma unroll
            for (int c = 0; c < 4; ++c) {
                int off = (rowoff + c * 32 + g * 8) ^ swz;
                s16x8 kh = *(s16x8*)&sKh[off];
                s16x8 kl = *(s16x8*)&sKl[off];
                a0 = __builtin_amdgcn_mfma_f32_16x16x32_bf16(kh, qh8[0][c], a0, 0, 0, 0);
                a1 = __builtin_amdgcn_mfma_f32_16x16x32_bf16(kh, qh8[1][c], a1, 0, 0, 0);
                a0 = __builtin_amdgcn_mfma_f32_16x16x32_bf16(kh, ql8[0][c], a0, 0, 0, 0);
                a1 = __builtin_amdgcn_mfma_f32_16x16x32_bf16(kh, ql8[1][c], a1, 0, 0, 0);
                a0 = __builtin_amdgcn_mfma_f32_16x16x32_bf16(kl, qh8[0][c], a0, 0, 0, 0);
                a1 = __builtin_amdgcn_mfma_f32_16x16x32_bf16(kl, qh8[1][c], a1, 0, 0, 0);
            }
            #pragma unroll
            for (int r = 0; r < 4; ++r) { p[0][s * 4 + r] = a0[r]; p[1][s * 4 + r] = a1[r]; }
        }

        // ---- online softmax (exp2 domain) + P -> LDS ----
        #pragma unroll
        for (int u = 0; u < 2; ++u) {
            u64 mw = u ? mw1 : mw0;
            unsigned mbits = 0;
            #pragma unroll
            for (int s = 0; s < 4; ++s)
                mbits |= (unsigned)((mw >> (s * 16 + 4 * g)) & 0xFull) << (4 * s);

            float tm = -INFINITY;
            #pragma unroll
            for (int i = 0; i < 16; ++i) {
                float sv = ((mbits >> i) & 1u) ? -INFINITY : p[u][i];
                p[u][i] = sv;
                tm = fmaxf(tm, sv);
            }
            tm = fmaxf(tm, __shfl_xor(tm, 16));
            tm = fmaxf(tm, __shfl_xor(tm, 32));

            float mold = mrun[u];
            bool defer = (mold > -INFINITY) && __all((int)(tm <= mold + 8.f));
            float m_use = mold;
            if (!defer) {   // wave-uniform branch
                float mnew = fmaxf(mold, tm);
                float corr = (mnew == -INFINITY) ? 0.f : __builtin_exp2f(mold - mnew);
                lsum[u] *= corr;
                #pragma unroll
                for (int j = 0; j < 4; ++j) {
                    float cj = __shfl(corr, 4 * g + j, 64);
                    #pragma unroll
                    for (int t = 0; t < 8; ++t) o[u][t][j] *= cj;
                }
                mrun[u] = mnew;
                m_use = mnew;
            }

            float psum = 0.f;
            #pragma unroll
            for (int i = 0; i < 16; ++i) {
                float pv = ((mbits >> i) & 1u) ? 0.f : __builtin_exp2f(p[u][i] - m_use);
                p[u][i] = pv;
                psum += pv;
            }
            psum += __shfl_xor(psum, 16);
            psum += __shfl_xor(psum, 32);
            lsum[u] += psum;

            u16* sP = sPb + (wave * 2 + u) * 1024;
            #pragma unroll
            for (int s = 0; s < 4; ++s) {
                ushort4 p4;
                p4.x = f2bf(p[u][s * 4 + 0]); p4.y = f2bf(p[u][s * 4 + 1]);
                p4.z = f2bf(p[u][s * 4 + 2]); p4.w = f2bf(p[u][s * 4 + 3]);
                int off = (qi * KT + s * 16 + 4 * g) ^ ((qi & 7) << 3);
                *(ushort4*)&sP[off] = p4;
            }
        }

        // ---- PV: V fragment reads shared by both q-groups ----
        u16* sP0 = sPb + (wave * 2 + 0) * 1024;
        u16* sP1 = sPb + (wave * 2 + 1) * 1024;
        #pragma unroll
        for (int h = 0; h < 2; ++h) {
            int offp = (qi * KT + h * 32 + g * 8) ^ ((qi & 7) << 3);
            s16x8 pa0 = *(s16x8*)&sP0[offp];
            s16x8 pa1 = *(s16x8*)&sP1[offp];
            #pragma unroll
            for (int t = 0; t < 8; ++t) {
                int d = t * 16 + qi;
                int offv = (d * KT + h * 32 + g * 8) ^ ((d & 7) << 3);
                s16x8 vb = *(s16x8*)&sVt_[offv];
                o[0][t] = __builtin_amdgcn_mfma_f32_16x16x32_bf16(pa0, vb, o[0][t], 0, 0, 0);
                o[1][t] = __builtin_amdgcn_mfma_f32_16x16x32_bf16(pa1, vb, o[1][t], 0, 0, 0);
            }
        }

        __syncthreads();   // staged loads complete (vmcnt0), all reads of cur done
        mw0 = nmw0; mw1 = nmw1;
        u16* tswap = cur; cur = nxt; nxt = tswap;
    }

    // ---- epilogue: out = acc / l ; fully-masked rows (l==0) -> 0 ----
    #pragma unroll
    for (int u = 0; u < 2; ++u)
        #pragma unroll
        for (int j = 0; j < 4; ++j) {
            float lj = __shfl(lsum[u], 4 * g + j, 64);
            float inv = (lj > 0.f) ? (1.0f / lj) : 0.f;
            int row = qbase + u * 16 + 4 * g + j;
            float* op = Out + ((size_t)b * NLQ + row) * ND + qi;
            #pragma unroll
            for (int t = 0; t < 8; ++t) op[t * 16] = o[u][t][j] * inv;
        }
#undef STAGE_TILE
}

// ==================== fallback (round-1 kernel) if ws too small ====================
__global__ void __launch_bounds__(256, 2)
attn_fallback(const float* __restrict__ Q, const float* __restrict__ K,
              const float* __restrict__ V, const unsigned char* __restrict__ Mb,
              float* __restrict__ Out)
{
    __shared__ u16 sKh[KT * ND];
    __shared__ u16 sKl[KT * ND];
    __shared__ u16 sVt[ND * KT];
    __shared__ u16 sP[4][16 * KT];

    const int tid  = threadIdx.x;
    const int wave = tid >> 6;
    const int ln   = tid & 63;
    const int g    = ln >> 4;
    const int qi   = ln & 15;

    const int bid   = blockIdx.x;
    const int b     = bid >> 5;
    const int qt    = bid & 31;
    const int qbase = qt * 64;
    const int qrow  = qbase + wave * 16 + qi;

    const bool maskByte = (g_maskflag != 0);

    s16x8 qh8[4], ql8[4];
    {
        const float* qp = Q + ((size_t)b * NLQ + qrow) * ND;
        #pragma unroll
        for (int c = 0; c < 4; ++c) {
            const float* p = qp + c * 32 + g * 8;
            float4 x0 = *(const float4*)(p);
            float4 x1 = *(const float4*)(p + 4);
            s16x8 h, l;
            SPLIT8(h, l, 0, x0.x * SCALE); SPLIT8(h, l, 1, x0.y * SCALE);
            SPLIT8(h, l, 2, x0.z * SCALE); SPLIT8(h, l, 3, x0.w * SCALE);
            SPLIT8(h, l, 4, x1.x * SCALE); SPLIT8(h, l, 5, x1.y * SCALE);
            SPLIT8(h, l, 6, x1.z * SCALE); SPLIT8(h, l, 7, x1.w * SCALE);
            qh8[c] = h; ql8[c] = l;
        }
    }

    f32x4 o[8];
    #pragma unroll
    for (int t = 0; t < 8; ++t) o[t] = (f32x4){0.f, 0.f, 0.f, 0.f};
    float m_run = -INFINITY, lsumv = 0.f;

    const float* kbp = K + (size_t)b * NLK * ND;
    const float* vbp = V + (size_t)b * NLK * ND;
    const size_t mrow = ((size_t)b * NLQ + qrow) * (size_t)NLK;

    for (int kt = 0; kt < NLK / KT; ++kt) {
        const int kb = kt * KT;
        __syncthreads();

        #pragma unroll
        for (int r = 0; r < 8; ++r) {
            int idx = r * 256 + tid;
            int kk  = idx >> 5;
            int d0  = (idx & 31) << 2;
            float4 x = *(const float4*)(kbp + (size_t)(kb + kk) * ND + d0);
            ushort4 h4, l4; u16 hb;
            hb = f2bf(x.x); h4.x = hb; l4.x = f2bf(x.x - bf2f(hb));
            hb = f2bf(x.y); h4.y = hb; l4.y = f2bf(x.y - bf2f(hb));
            hb = f2bf(x.z); h4.z = hb; l4.z = f2bf(x.z - bf2f(hb));
            hb = f2bf(x.w); h4.w = hb; l4.w = f2bf(x.w - bf2f(hb));
            int off = (kk * ND + d0) ^ ((kk & 7) << 3);
            *(ushort4*)&sKh[off] = h4;
            *(ushort4*)&sKl[off] = l4;
        }
        #pragma unroll
        for (int r = 0; r < 2; ++r) {
            int idx = r * 256 + tid;
            int kk0 = (idx >> 5) << 2;
            int d0  = (idx & 31) << 2;
            const float* vp = vbp + (size_t)(kb + kk0) * ND + d0;
            float4 r0 = *(const float4*)(vp);
            float4 r1 = *(const float4*)(vp + ND);
            float4 r2 = *(const float4*)(vp + 2 * ND);
            float4 r3 = *(const float4*)(vp + 3 * ND);
            ushort4 cv;
            cv.x = f2bf(r0.x); cv.y = f2bf(r1.x); cv.z = f2bf(r2.x); cv.w = f2bf(r3.x);
            { int d = d0;     *(ushort4*)&sVt[(d * KT + kk0) ^ ((d & 7) << 3)] = cv; }
            cv.x = f2bf(r0.y); cv.y = f2bf(r1.y); cv.z = f2bf(r2.y); cv.w = f2bf(r3.y);
            { int d = d0 + 1; *(ushort4*)&sVt[(d * KT + kk0) ^ ((d & 7) << 3)] = cv; }
            cv.x = f2bf(r0.z); cv.y = f2bf(r1.z); cv.z = f2bf(r2.z); cv.w = f2bf(r3.z);
            { int d = d0 + 2; *(ushort4*)&sVt[(d * KT + kk0) ^ ((d & 7) << 3)] = cv; }
            cv.x = f2bf(r0.w); cv.y = f2bf(r1.w); cv.z = f2bf(r2.w); cv.w = f2bf(r3.w);
            { int d = d0 + 3; *(ushort4*)&sVt[(d * KT + kk0) ^ ((d & 7) << 3)] = cv; }
        }
        __syncthreads();

        unsigned maskbits = 0;
        if (maskByte) {
            #pragma unroll
            for (int s = 0; s < 4; ++s) {
                unsigned mm = *(const unsigned int*)(Mb + mrow + (size_t)(kb + s * 16 + 4 * g));
                #pragma unroll
                for (int j = 0; j < 4; ++j)
                    maskbits |= (((mm >> (8 * j)) & 0xFFu) ? 1u : 0u) << (s * 4 + j);
            }
        } else {
            const int* Mi = (const int*)Mb;
            #pragma unroll
            for (int s = 0; s < 4; ++s) {
                int4 mm = *(const int4*)(Mi + mrow + (size_t)(kb + s * 16 + 4 * g));
                if (mm.x) maskbits |= 1u << (s * 4 + 0);
                if (mm.y) maskbits |= 1u << (s * 4 + 1);
                if (mm.z) maskbits |= 1u << (s * 4 + 2);
                if (mm.w) maskbits |= 1u << (s * 4 + 3);
            }
        }

        float p[16];
        #pragma unroll
        for (int s = 0; s < 4; ++s) {
            f32x4 acc = (f32x4){0.f, 0.f, 0.f, 0.f};
            int rowoff = (s * 16 + qi) * ND;
            int swz = ((s * 16 + qi) & 7) << 3;
            #pragma unroll
            for (int c = 0; c < 4; ++c) {
                int off = (rowoff + c * 32 + g * 8) ^ swz;
                s16x8 kh = *(s16x8*)&sKh[off];
                s16x8 kl = *(s16x8*)&sKl[off];
                acc = __builtin_amdgcn_mfma_f32_16x16x32_bf16(kh, qh8[c], acc, 0, 0, 0);
                acc = __builtin_amdgcn_mfma_f32_16x16x32_bf16(kh, ql8[c], acc, 0, 0, 0);
                acc = __builtin_amdgcn_mfma_f32_16x16x32_bf16(kl, qh8[c], acc, 0, 0, 0);
            }
            p[s * 4 + 0] = acc[0]; p[s * 4 + 1] = acc[1];
            p[s * 4 + 2] = acc[2]; p[s * 4 + 3] = acc[3];
        }

        float tmax = -INFINITY;
        #pragma unroll
        for (int i = 0; i < 16; ++i) {
            float sv = ((maskbits >> i) & 1u) ? -INFINITY : p[i];
            p[i] = sv;
            tmax = fmaxf(tmax, sv);
        }
        tmax = fmaxf(tmax, __shfl_xor(tmax, 16));
        tmax = fmaxf(tmax, __shfl_xor(tmax, 32));
        float mnew = fmaxf(m_run, tmax);
        float corr = (mnew == -INFINITY) ? 0.f : __expf(m_run - mnew);
        float psum = 0.f;
        #pragma unroll
        for (int i = 0; i < 16; ++i) {
            float pv = ((maskbits >> i) & 1u) ? 0.f : __expf(p[i] - mnew);
            p[i] = pv;
            psum += pv;
        }
        psum += __shfl_xor(psum, 16);
        psum += __shfl_xor(psum, 32);
        lsumv = lsumv * corr + psum;
        m_run = mnew;

        #pragma unroll
        for (int j = 0; j < 4; ++j) {
            float cj = __shfl(corr, 4 * g + j, 64);
            #pragma unroll
            for (int t = 0; t < 8; ++t) o[t][j] *= cj;
        }

        #pragma unroll
        for (int s = 0; s < 4; ++s) {
            ushort4 p4;
            p4.x = f2bf(p[s * 4 + 0]); p4.y = f2bf(p[s * 4 + 1]);
            p4.z = f2bf(p[s * 4 + 2]); p4.w = f2bf(p[s * 4 + 3]);
            int off = (qi * KT + s * 16 + 4 * g) ^ ((qi & 7) << 3);
            *(ushort4*)&sP[wave][off] = p4;
        }
        #pragma unroll
        for (int h = 0; h < 2; ++h) {
            int offp = (qi * KT + h * 32 + g * 8) ^ ((qi & 7) << 3);
            s16x8 pa = *(s16x8*)&sP[wave][offp];
            #pragma unroll
            for (int t = 0; t < 8; ++t) {
                int d = t * 16 + qi;
                int offv = (d * KT + h * 32 + g * 8) ^ ((d & 7) << 3);
                s16x8 vb = *(s16x8*)&sVt[offv];
                o[t] = __builtin_amdgcn_mfma_f32_16x16x32_bf16(pa, vb, o[t], 0, 0, 0);
            }
        }
    }

    #pragma unroll
    for (int j = 0; j < 4; ++j) {
        float lj = __shfl(lsumv, 4 * g + j, 64);
        float inv = (lj > 0.f) ? (1.0f / lj) : 0.f;
        int row = qbase + wave * 16 + 4 * g + j;
        float* op = Out + ((size_t)b * NLQ + row) * ND + qi;
        #pragma unroll
        for (int t = 0; t < 8; ++t) op[t * 16] = o[t][j] * inv;
    }
}

extern "C" void kernel_launch(void* const* d_in, const int* in_sizes, int n_in,
                              void* d_out, int out_size, void* d_ws, size_t ws_size,
                              hipStream_t stream) {
    (void)in_sizes; (void)n_in; (void)out_size;
    const float* Q = (const float*)d_in[0];
    const float* K = (const float*)d_in[1];
    const float* V = (const float*)d_in[2];
    const unsigned char* M = (const unsigned char*)d_in[3];
    float* Out = (float*)d_out;

    zero_flag_kernel<<<1, 64, 0, stream>>>();
    detect_mask_kernel<<<64, 256, 0, stream>>>(M);

    // ws: Khi 16M | Klo 16M | Vt 16M | Bits 16M
    const size_t WS_NEED = (size_t)64 * 1024 * 1024;
    if (ws_size >= WS_NEED) {
        u16* Khi = (u16*)d_ws;
        u16* Klo = Khi + 8388608;
        u16* Vt  = Klo + 8388608;
        u64* Bits = (u64*)(Vt + 8388608);
        maskbits_kernel<<<4096, 256, 0, stream>>>(M, Bits);
        ksplit_kernel<<<4096, 256, 0, stream>>>(K, Khi, Klo);
        vtrans_kernel<<<4096, 256, 0, stream>>>(V, Vt);
        hipFuncSetAttribute((const void*)attn3_kernel,
                            hipFuncAttributeMaxDynamicSharedMemorySize, 131072);
        attn3_kernel<<<256, 512, 131072, stream>>>(Q, Bits, Out, Khi, Klo, Vt);
    } else {
        attn_fallback<<<1024, 256, 0, stream>>>(Q, K, V, M, Out);
    }
}